// Round 5
// baseline (511.875 us; speedup 1.0000x reference)
//
#include <hip/hip_runtime.h>
#include <math.h>

// Quantized ConvBlock, round 8: depth-2 staging pipeline for conv_main.
//   R0-R4 post-mortem: MfmaUtil pinned ~38% across four schedules (2blk, phases,
//   3blk+L2-weights). Invariant = ONE compute-phase of staging slack; every chunk
//   boundary exposes L2/HBM latency, and the block barrier propagates it to all waves.
//   Fix: xs triple-buffered, x(cc+2) issued at iter cc (2 phases of slack); weights
//   back in LDS via gl_lds (reg-path weight loads would force-drain the in-order vmcnt
//   pipeline); per-iter issue = w(cc+1) [3/wave] then x(cc+2) [5/wave]; counted
//   s_waitcnt vmcnt(13) (8 at cc=6, 0 at cc=7) keeps 13 loads in flight across
//   barriers. K-loop fully unrolled so all vmcnt/buffer indices are literals.
//
// ws layout (bytes):
//   0        : xmax bits (uint)             [memset to 0]
//   256      : fw[256] floats
//   2048     : wq_a  f16 [o][tap][c]        (fallback layout)
//   655360   : wq_b  f16 [cc][tap][o][c16]  (linear)
//   1572864  : ZP zero page (2 KB, memset)
//   2097152  : xq    f16 [n][cc][h][w][c16]

#define FW_NUM 20017.23017802413f
#define FX_NUM 835.5924988699913f
#define WQA_OFF 2048
#define WQB_OFF (640 * 1024)
#define ZP_OFF  (1536 * 1024)
#define XQ_OFF  (2 * 1024 * 1024)
#define XQ_BYTES 67108864ull

// fallback-kernel tile params (R2 kernel, kept verbatim)
#define CK  16
#define CKP 24
#define JW  130

typedef _Float16 half8 __attribute__((ext_vector_type(8)));
typedef _Float16 half4 __attribute__((ext_vector_type(4)));
typedef float floatx16 __attribute__((ext_vector_type(16)));

__device__ __forceinline__ void gl_lds16(const void* g, void* s) {
    __builtin_amdgcn_global_load_lds((const __attribute__((address_space(1))) void*)g,
                                     (__attribute__((address_space(3))) void*)s, 16, 0, 0);
}

__global__ void xmax_kernel(const float* __restrict__ x, unsigned int* wsu, int n4) {
    int tid = blockIdx.x * blockDim.x + threadIdx.x;
    int stride = gridDim.x * blockDim.x;
    const float4* x4 = (const float4*)x;
    float m = 0.f;
    for (int i = tid; i < n4; i += stride) {
        float4 v = x4[i];
        m = fmaxf(m, fmaxf(fmaxf(fabsf(v.x), fabsf(v.y)), fmaxf(fabsf(v.z), fabsf(v.w))));
    }
    #pragma unroll
    for (int off = 32; off >= 1; off >>= 1)
        m = fmaxf(m, __shfl_down(m, off, 64));
    __shared__ float sm[4];
    if ((threadIdx.x & 63) == 0) sm[threadIdx.x >> 6] = m;
    __syncthreads();
    if (threadIdx.x == 0) {
        m = fmaxf(fmaxf(sm[0], sm[1]), fmaxf(sm[2], sm[3]));
        atomicMax(wsu, __float_as_uint(m));
    }
}

// one block per o (256 blocks, 128 threads; t = input channel c)
__global__ void wq_kernel(const float* __restrict__ W, float* wsf, int big) {
    int o = blockIdx.x;
    int t = threadIdx.x;
    const float* wrow = W + o * 1152;
    float wv[9];
    float s = 0.f;
    #pragma unroll
    for (int k = 0; k < 9; k++) { wv[k] = wrow[t * 9 + k]; s += fabsf(wv[k]); }
    #pragma unroll
    for (int off = 32; off >= 1; off >>= 1) s += __shfl_down(s, off, 64);
    __shared__ float sred[2];
    __shared__ float sfw;
    if ((t & 63) == 0) sred[t >> 6] = s;
    __syncthreads();
    if (t == 0) {
        float wsum = sred[0] + sred[1];
        if (wsum == 0.f) wsum = 1.f;
        float fw = FW_NUM / wsum;
        wsf[64 + o] = fw;
        sfw = fw;
    }
    __syncthreads();
    float fw = sfw;
    _Float16* wqa = (_Float16*)((char*)wsf + WQA_OFF);   // [o][tap][c]
    _Float16* wqb = (_Float16*)((char*)wsf + WQB_OFF);   // [cc][tap][o][c16] linear
    #pragma unroll
    for (int k = 0; k < 9; k++) {
        _Float16 hv = (_Float16)rintf(wv[k] * fw);       // rintf = RNE = jnp.round
        wqa[(o * 9 + k) * 128 + t] = hv;
        if (big)
            wqb[(((t >> 4) * 9 + k) * 256 + o) * 16 + (t & 15)] = hv;
    }
}

// block = one (n, cc, h): quantize 16 c-planes' row h into [w][c16] (4 KB contiguous)
__global__ void quantx_kernel(const float* __restrict__ x, const float* __restrict__ wsf,
                              _Float16* __restrict__ xq) {
    int bid = blockIdx.x;           // (n*8 + cc)*128 + h
    int h  = bid & 127;
    int cc = (bid >> 7) & 7;
    int n  = bid >> 10;
    float xmax = __uint_as_float(((const unsigned int*)wsf)[0]);
    float fx = xmax > 0.f ? FX_NUM / xmax : 1.0f;
    int w = threadIdx.x;            // 128
    const float* xp = x + ((size_t)(n * 128 + cc * 16) * 128 + h) * 128 + w;
    half8 v0, v1;
    #pragma unroll
    for (int ci = 0; ci < 8; ci++)  v0[ci] = (_Float16)rintf(fx * xp[(size_t)ci * 16384]);
    #pragma unroll
    for (int ci = 8; ci < 16; ci++) v1[ci - 8] = (_Float16)rintf(fx * xp[(size_t)ci * 16384]);
    _Float16* op = xq + ((size_t)bid * 128 + w) * 16;
    *(half8*)op = v0;
    *(half8*)(op + 8) = v1;
}

__global__ __launch_bounds__(256, 2) void conv_main(const _Float16* __restrict__ xq,
                                                    const float* __restrict__ bias,
                                                    const float* __restrict__ wsf,
                                                    float* __restrict__ out) {
    // xs: 3 buffers x 18 rows x 68 slots(16B) (= 19584 B used, 20480 B staged incl pad).
    //   slot = r*68 + spi; spi -> input w = w0 + (spi>>1) - 1, c-half = spi&1.
    // wl: 2 buffers x 9 taps x 32 o x 32 B = 9216 B each; wdump = shared dummy dest.
    __shared__ __align__(16) _Float16 xs[3][10240];   // 61440 B
    __shared__ __align__(16) _Float16 wl[2][4608];    // 18432 B
    __shared__ __align__(16) _Float16 wdump[512];     // 1024 B
    __shared__ float sc[32], bz[32];                  // 256 B   (total 81152 -> 2 blk/CU)

    float xmax = __uint_as_float(((const unsigned int*)wsf)[0]);
    float fx = xmax > 0.f ? FX_NUM / xmax : 1.0f;

    // XCD-contiguous remap (4096 % 8 == 0 -> bijective); o fastest so one XCD's L2
    // serves all 8 o-blocks of a pixel tile.
    int bx0 = blockIdx.x;
    int bx = (bx0 & 7) * 512 + (bx0 >> 3);
    int o0 = (bx & 7) << 5;
    int w0 = ((bx >> 3) & 3) << 5;
    int h0 = ((bx >> 5) & 7) << 4;
    int n  = bx >> 8;

    int tid = threadIdx.x;
    int lane = tid & 63;
    int wv = tid >> 6;
    int m32 = lane & 31;
    int q2 = lane >> 5;

    const char* wsb = (const char*)wsf;

    // ---- x staging: 5 gl_lds/wave (slots s = wv + 4k), chunk-0 offsets, +524288/chunk
    int xoff[5];
    int xstr[5];
    #pragma unroll
    for (int k = 0; k < 5; ++k) {
        int s = wv + 4 * k;                  // 0..19
        int slot = s * 64 + lane;            // 0..1279
        int r = (slot * 241) >> 14;          // exact /68 for slot < 1224
        int spi = slot - r * 68;
        int h = h0 + r - 1;
        int w = w0 + (spi >> 1) - 1;
        bool ok = (slot < 1224) && (h >= 0) && (h < 128) && (w >= 0) && (w < 128);
        if (ok) {
            xoff[k] = XQ_OFF + n * 4194304 + (h * 128 + w) * 32 + (spi & 1) * 16;
            xstr[k] = 524288;
        } else {
            xoff[k] = ZP_OFF + lane * 16;
            xstr[k] = 0;
        }
    }
    // ---- w staging: 3 gl_lds/wave (segs t = wv + 4k; t<9 real taps, t>=9 dummy)
    int woff[3];
    int wstr[3];
    #pragma unroll
    for (int k = 0; k < 3; ++k) {
        int t = wv + 4 * k;                  // 0..11
        if (t < 9) {
            woff[k] = WQB_OFF + t * 8192 + o0 * 32 + lane * 16;
            wstr[k] = 73728;
        } else {
            woff[k] = ZP_OFF + lane * 16;
            wstr[k] = 0;
        }
    }

    auto stage_x = [&](int tb) {
        #pragma unroll
        for (int k = 0; k < 5; ++k) {
            int s = wv + 4 * k;
            gl_lds16(wsb + xoff[k], (char*)&xs[tb][0] + s * 1024);
            xoff[k] += xstr[k];
        }
    };
    auto stage_w = [&](int tb) {
        #pragma unroll
        for (int k = 0; k < 3; ++k) {
            int t = wv + 4 * k;
            char* dst = (t < 9) ? ((char*)&wl[tb][0] + t * 1024) : (char*)&wdump[0];
            gl_lds16(wsb + woff[k], dst);
            woff[k] += wstr[k];
        }
    };

    // ---- scale/bias to LDS (visible by first barrier; read only in epilogue)
    if (tid < 32) {
        float fwv = wsf[64 + o0 + tid];
        sc[tid] = 1.0f / (fx * fwv);
        bz[tid] = bias[o0 + tid];
    }

    floatx16 acc[4];
    #pragma unroll
    for (int p = 0; p < 4; ++p)
        #pragma unroll
        for (int e = 0; e < 16; ++e) acc[p][e] = 0.f;

    // ---- prologue: w(0), x(0), x(1) in flight (issue order matters for vmcnt math)
    stage_w(0);
    stage_x(0);
    stage_x(1);

    // ---- K loop, fully unrolled. Per iter cc:
    //   barrier A; stage_w(cc+1); stage_x(cc+2); vmcnt(N); barrier E; compute chunk cc.
    //   N = |{x(cc+1), w(cc+1), x(cc+2)}| = 13 (cc<6), 8 (cc=6), 0 (cc=7): in-order
    //   retirement => w(cc) retired => x(cc) retired => buffers cc valid after barrier E.
    #pragma unroll
    for (int cc = 0; cc < 8; ++cc) {
        __builtin_amdgcn_s_barrier();                       // recycled buffers free
        if (cc < 7) stage_w((cc + 1) & 1);
        if (cc < 6) stage_x((cc + 2) % 3);
        if (cc < 6)       asm volatile("s_waitcnt vmcnt(13)" ::: "memory");
        else if (cc == 6) asm volatile("s_waitcnt vmcnt(8)" ::: "memory");
        else              asm volatile("s_waitcnt vmcnt(0)" ::: "memory");
        __builtin_amdgcn_s_barrier();                       // chunk cc buffers valid
        __builtin_amdgcn_sched_barrier(0);                  // no ds_read hoist above

        const char* xb = (const char*)&xs[cc % 3][0] + wv * (4 * 1088);
        const char* wb = (const char*)&wl[cc & 1][0];
        #pragma unroll
        for (int kw = 0; kw < 3; ++kw) {
            half8 xf[6];
            #pragma unroll
            for (int srow = 0; srow < 6; ++srow)
                xf[srow] = *(const half8*)(xb + srow * 1088 + (m32 + kw) * 32 + q2 * 16);
            half8 wf[3];
            #pragma unroll
            for (int kh = 0; kh < 3; ++kh)
                wf[kh] = *(const half8*)(wb + (kh * 3 + kw) * 1024 + m32 * 32 + q2 * 16);
            __builtin_amdgcn_s_setprio(1);
            #pragma unroll
            for (int kh = 0; kh < 3; ++kh) {
                #pragma unroll
                for (int p = 0; p < 4; ++p)
                    acc[p] = __builtin_amdgcn_mfma_f32_32x32x16_f16(wf[kh], xf[p + kh], acc[p], 0, 0, 0);
            }
            __builtin_amdgcn_s_setprio(0);
        }
    }

    // ---- epilogue: D row = o (reg), col = pixel (lane) -> coalesced stores
    #pragma unroll
    for (int e = 0; e < 16; ++e) {
        int o_loc = (e & 3) + 8 * (e >> 2) + 4 * q2;
        float scale = sc[o_loc];
        float bv = bz[o_loc];
        #pragma unroll
        for (int p = 0; p < 4; ++p) {
            int h = h0 + wv * 4 + p;
            float v = fmaxf(fmaf(acc[p][e], scale, bv), 0.f);
            out[(((size_t)(n * 256 + o0 + o_loc)) * 128 + h) * 128 + w0 + m32] = v;
        }
    }
}

// ---------------- fallback (R2 kernel, used if ws too small) ----------------
__global__ __launch_bounds__(256, 2) void conv_fallback(const float* __restrict__ x,
                                                        const float* __restrict__ bias,
                                                        const float* __restrict__ wsf,
                                                        float* __restrict__ out) {
    __shared__ __align__(16) _Float16 xs[6 * JW * CKP];
    __shared__ __align__(16) _Float16 wlds[9 * 64 * CKP];

    const unsigned int* wsu = (const unsigned int*)wsf;
    float xmax = __uint_as_float(wsu[0]);
    float fx = xmax > 0.f ? FX_NUM / xmax : 1.0f;

    int bx = blockIdx.x;
    int n  = bx >> 5;
    int h0 = (bx & 31) << 2;
    int o0 = blockIdx.y << 6;

    int tid  = threadIdx.x;
    int lane = tid & 63;
    int wave = tid >> 6;
    int m32  = lane & 31;
    int q2   = lane >> 5;

    const _Float16* wq16 = (const _Float16*)((const char*)wsf + WQA_OFF);
    const float* xn = x + (size_t)n * (128 * 128 * 128);

    floatx16 acc[4][2];
    #pragma unroll
    for (int mt = 0; mt < 4; mt++)
        #pragma unroll
        for (int nt = 0; nt < 2; nt++)
            #pragma unroll
            for (int e = 0; e < 16; e++) acc[mt][nt][e] = 0.f;

    if (tid < 192) {
        int r = tid >> 5;
        int s = tid & 31;
        int c = s & 15;
        int j = (s >> 4) ? (JW - 1) : 0;
        xs[(r * JW + j) * CKP + c] = (_Float16)0.f;
    }

    for (int c0 = 0; c0 < 128; c0 += CK) {
        __syncthreads();
        #pragma unroll
        for (int it = 0; it < 12; ++it) {
            int idx = tid + it * 256;
            int j  = (idx & 127) + 1;
            int c4 = (idx >> 7) & 3;
            int r  = idx >> 9;
            int h  = h0 + r - 1;
            float v0 = 0.f, v1 = 0.f, v2 = 0.f, v3 = 0.f;
            if (h >= 0 && h < 128) {
                const float* xp = xn + (size_t)(c0 + c4 * 4) * 16384 + h * 128 + (j - 1);
                v0 = xp[0]; v1 = xp[16384]; v2 = xp[32768]; v3 = xp[49152];
            }
            half4 hv;
            hv[0] = (_Float16)rintf(fx * v0);
            hv[1] = (_Float16)rintf(fx * v1);
            hv[2] = (_Float16)rintf(fx * v2);
            hv[3] = (_Float16)rintf(fx * v3);
            *(half4*)&xs[(r * JW + j) * CKP + c4 * 4] = hv;
        }
        #pragma unroll
        for (int it = 0; it < 5; ++it) {
            int idx = tid + it * 256;
            if (idx < 1152) {
                int o   = idx / 18;
                int rem = idx - o * 18;
                int tap = rem >> 1;
                int g   = rem & 1;
                half8 v = *(const half8*)(wq16 + ((size_t)(o0 + o) * 9 + tap) * 128 + c0 + g * 8);
                *(half8*)&wlds[(tap * 64 + o) * CKP + g * 8] = v;
            }
        }
        __syncthreads();

        const _Float16* xbase = &xs[(wave * JW + m32) * CKP + q2 * 8];
        const _Float16* wbase = &wlds[m32 * CKP + q2 * 8];
        #pragma unroll
        for (int kh = 0; kh < 3; ++kh) {
            #pragma unroll
            for (int kw = 0; kw < 3; ++kw) {
                int tap = kh * 3 + kw;
                half8 b0 = *(const half8*)(wbase + (tap * 64 +  0) * CKP);
                half8 b1 = *(const half8*)(wbase + (tap * 64 + 32) * CKP);
                #pragma unroll
                for (int mt = 0; mt < 4; ++mt) {
                    half8 a = *(const half8*)(xbase + (kh * JW + kw + mt * 32) * CKP);
                    acc[mt][0] = __builtin_amdgcn_mfma_f32_32x32x16_f16(a, b0, acc[mt][0], 0, 0, 0);
                    acc[mt][1] = __builtin_amdgcn_mfma_f32_32x32x16_f16(a, b1, acc[mt][1], 0, 0, 0);
                }
            }
        }
    }

    int h = h0 + wave;
    #pragma unroll
    for (int nt = 0; nt < 2; ++nt) {
        int o = o0 + nt * 32 + m32;
        float fwv = wsf[64 + o];
        float scale = 1.0f / (fx * fwv);
        float bv = bias[o];
        float* op = out + (((size_t)n * 256 + o) * 128 + h) * 128;
        #pragma unroll
        for (int mt = 0; mt < 4; ++mt) {
            #pragma unroll
            for (int g = 0; g < 4; ++g) {
                int w = mt * 32 + 8 * g + 4 * q2;
                float4 r;
                r.x = fmaxf(fmaf(acc[mt][nt][4 * g + 0], scale, bv), 0.f);
                r.y = fmaxf(fmaf(acc[mt][nt][4 * g + 1], scale, bv), 0.f);
                r.z = fmaxf(fmaf(acc[mt][nt][4 * g + 2], scale, bv), 0.f);
                r.w = fmaxf(fmaf(acc[mt][nt][4 * g + 3], scale, bv), 0.f);
                *(float4*)(op + w) = r;
            }
        }
    }
}

extern "C" void kernel_launch(void* const* d_in, const int* in_sizes, int n_in,
                              void* d_out, int out_size, void* d_ws, size_t ws_size,
                              hipStream_t stream) {
    const float* x = (const float*)d_in[0];   // [16,128,128,128]
    const float* W = (const float*)d_in[1];   // [256,128,3,3]
    const float* b = (const float*)d_in[2];   // [256]
    float* out = (float*)d_out;
    float* wsf = (float*)d_ws;

    int big = (ws_size >= (size_t)XQ_OFF + XQ_BYTES) ? 1 : 0;

    hipMemsetAsync(d_ws, 0, 256, stream);     // xmax slot (ws poisoned 0xAA)
    if (big)
        hipMemsetAsync((char*)d_ws + ZP_OFF, 0, 2048, stream);   // zero page for OOB staging

    xmax_kernel<<<1024, 256, 0, stream>>>(x, (unsigned int*)d_ws, (16 * 128 * 128 * 128) / 4);
    wq_kernel<<<256, 128, 0, stream>>>(W, wsf, big);

    if (big) {
        _Float16* xq = (_Float16*)((char*)d_ws + XQ_OFF);
        quantx_kernel<<<16 * 8 * 128, 128, 0, stream>>>(x, wsf, xq);
        conv_main<<<4096, 256, 0, stream>>>(xq, b, wsf, out);
    } else {
        dim3 grid(512, 4);
        conv_fallback<<<grid, 256, 0, stream>>>(x, b, wsf, out);
    }
}

// Round 6
// 509.467 us; speedup vs baseline: 1.0047x; 1.0047x over previous
//
#include <hip/hip_runtime.h>
#include <math.h>

// Quantized ConvBlock, round 9: conflict-free LDS layouts for conv_main.
//   R0-R5 post-mortem: all five schedule variants pinned at MfmaUtil ~38% / ~178 us.
//   Root cause (bank arithmetic): xf/wf reads at per-lane byte m32*32 + q2*16 ->
//   (m32%4)*32 mod 128 -> 8-way bank conflict on all 27 ds_read_b128/wave/chunk;
//   13824 reads/CU x ~30cy = 415k cy == measured 425k cy. LDS-conflict-bound.
//   Fix (layout only, schedule identical to R8/R5):
//     x rows:  [q(2)][j(34)][c8]  -> read row + q2*544 + (m32+kw)*16   (contig 512B/half-wave)
//     weights: wq_b [cc][tap][q][o][c8] -> per-tap LDS [q][o][16B],
//              read tap*1024 + q2*512 + m32*16                         (contig 1024B/wave)
//   Both match the m134 conflict-free lane*16 baseline (~12cy/b128).
//
// ws layout (bytes):
//   0        : xmax bits (uint)             [memset to 0]
//   256      : fw[256] floats
//   2048     : wq_a  f16 [o][tap][c]        (fallback layout)
//   655360   : wq_b  f16 [cc][tap][q][o][c8]
//   1572864  : ZP zero page (2 KB, memset)
//   2097152  : xq    f16 [n][cc][h][w][c16]

#define FW_NUM 20017.23017802413f
#define FX_NUM 835.5924988699913f
#define WQA_OFF 2048
#define WQB_OFF (640 * 1024)
#define ZP_OFF  (1536 * 1024)
#define XQ_OFF  (2 * 1024 * 1024)
#define XQ_BYTES 67108864ull

// fallback-kernel tile params (R2 kernel, kept verbatim)
#define CK  16
#define CKP 24
#define JW  130

typedef _Float16 half8 __attribute__((ext_vector_type(8)));
typedef _Float16 half4 __attribute__((ext_vector_type(4)));
typedef float floatx16 __attribute__((ext_vector_type(16)));

__device__ __forceinline__ void gl_lds16(const void* g, void* s) {
    __builtin_amdgcn_global_load_lds((const __attribute__((address_space(1))) void*)g,
                                     (__attribute__((address_space(3))) void*)s, 16, 0, 0);
}

__global__ void xmax_kernel(const float* __restrict__ x, unsigned int* wsu, int n4) {
    int tid = blockIdx.x * blockDim.x + threadIdx.x;
    int stride = gridDim.x * blockDim.x;
    const float4* x4 = (const float4*)x;
    float m = 0.f;
    for (int i = tid; i < n4; i += stride) {
        float4 v = x4[i];
        m = fmaxf(m, fmaxf(fmaxf(fabsf(v.x), fabsf(v.y)), fmaxf(fabsf(v.z), fabsf(v.w))));
    }
    #pragma unroll
    for (int off = 32; off >= 1; off >>= 1)
        m = fmaxf(m, __shfl_down(m, off, 64));
    __shared__ float sm[4];
    if ((threadIdx.x & 63) == 0) sm[threadIdx.x >> 6] = m;
    __syncthreads();
    if (threadIdx.x == 0) {
        m = fmaxf(fmaxf(sm[0], sm[1]), fmaxf(sm[2], sm[3]));
        atomicMax(wsu, __float_as_uint(m));
    }
}

// one block per o (256 blocks, 128 threads; t = input channel c)
__global__ void wq_kernel(const float* __restrict__ W, float* wsf, int big) {
    int o = blockIdx.x;
    int t = threadIdx.x;
    const float* wrow = W + o * 1152;
    float wv[9];
    float s = 0.f;
    #pragma unroll
    for (int k = 0; k < 9; k++) { wv[k] = wrow[t * 9 + k]; s += fabsf(wv[k]); }
    #pragma unroll
    for (int off = 32; off >= 1; off >>= 1) s += __shfl_down(s, off, 64);
    __shared__ float sred[2];
    __shared__ float sfw;
    if ((t & 63) == 0) sred[t >> 6] = s;
    __syncthreads();
    if (t == 0) {
        float wsum = sred[0] + sred[1];
        if (wsum == 0.f) wsum = 1.f;
        float fw = FW_NUM / wsum;
        wsf[64 + o] = fw;
        sfw = fw;
    }
    __syncthreads();
    float fw = sfw;
    _Float16* wqa = (_Float16*)((char*)wsf + WQA_OFF);   // [o][tap][c]
    _Float16* wqb = (_Float16*)((char*)wsf + WQB_OFF);   // [cc][tap][q][o][c8]
    int cc = t >> 4;
    int q  = (t >> 3) & 1;
    int c8 = t & 7;
    #pragma unroll
    for (int k = 0; k < 9; k++) {
        _Float16 hv = (_Float16)rintf(wv[k] * fw);       // rintf = RNE = jnp.round
        wqa[(o * 9 + k) * 128 + t] = hv;
        if (big)
            wqb[((((cc * 9 + k) * 2 + q) * 256) + o) * 8 + c8] = hv;
    }
}

// block = one (n, cc, h): quantize 16 c-planes' row h into [w][c16] (4 KB contiguous)
__global__ void quantx_kernel(const float* __restrict__ x, const float* __restrict__ wsf,
                              _Float16* __restrict__ xq) {
    int bid = blockIdx.x;           // (n*8 + cc)*128 + h
    int h  = bid & 127;
    int cc = (bid >> 7) & 7;
    int n  = bid >> 10;
    float xmax = __uint_as_float(((const unsigned int*)wsf)[0]);
    float fx = xmax > 0.f ? FX_NUM / xmax : 1.0f;
    int w = threadIdx.x;            // 128
    const float* xp = x + ((size_t)(n * 128 + cc * 16) * 128 + h) * 128 + w;
    half8 v0, v1;
    #pragma unroll
    for (int ci = 0; ci < 8; ci++)  v0[ci] = (_Float16)rintf(fx * xp[(size_t)ci * 16384]);
    #pragma unroll
    for (int ci = 8; ci < 16; ci++) v1[ci - 8] = (_Float16)rintf(fx * xp[(size_t)ci * 16384]);
    _Float16* op = xq + ((size_t)bid * 128 + w) * 16;
    *(half8*)op = v0;
    *(half8*)(op + 8) = v1;
}

__global__ __launch_bounds__(256, 2) void conv_main(const _Float16* __restrict__ xq,
                                                    const float* __restrict__ bias,
                                                    const float* __restrict__ wsf,
                                                    float* __restrict__ out) {
    // xs: 3 buffers x 18 rows x 1088 B; row layout [q(2)][j(34)][c8] (544 B per q-half).
    //   slot(16B) = r*68 + spi; q = spi>=34, j = spi - q*34 -> input w = w0 + j - 1.
    // wl: 2 buffers x 9 taps x 1024 B; per-tap layout [q(2)][o(32)][16B].
    __shared__ __align__(16) _Float16 xs[3][10240];   // 61440 B
    __shared__ __align__(16) _Float16 wl[2][4608];    // 18432 B
    __shared__ __align__(16) _Float16 wdump[512];     // 1024 B
    __shared__ float sc[32], bz[32];                  // 256 B   (total 81152 -> 2 blk/CU)

    float xmax = __uint_as_float(((const unsigned int*)wsf)[0]);
    float fx = xmax > 0.f ? FX_NUM / xmax : 1.0f;

    // XCD-contiguous remap (4096 % 8 == 0 -> bijective); o fastest so one XCD's L2
    // serves all 8 o-blocks of a pixel tile.
    int bx0 = blockIdx.x;
    int bx = (bx0 & 7) * 512 + (bx0 >> 3);
    int o0 = (bx & 7) << 5;
    int w0 = ((bx >> 3) & 3) << 5;
    int h0 = ((bx >> 5) & 7) << 4;
    int n  = bx >> 8;

    int tid = threadIdx.x;
    int lane = tid & 63;
    int wv = tid >> 6;
    int m32 = lane & 31;
    int q2 = lane >> 5;

    const char* wsb = (const char*)wsf;

    // ---- x staging: 5 gl_lds/wave (slots s = wv + 4k), chunk-0 offsets, +524288/chunk
    int xoff[5];
    int xstr[5];
    #pragma unroll
    for (int k = 0; k < 5; ++k) {
        int s = wv + 4 * k;                  // 0..19
        int slot = s * 64 + lane;            // 0..1279
        int r = (slot * 241) >> 14;          // exact /68 for slot < 1224
        int spi = slot - r * 68;
        int q = (spi >= 34) ? 1 : 0;
        int j = spi - q * 34;
        int h = h0 + r - 1;
        int w = w0 + j - 1;
        bool ok = (slot < 1224) && (h >= 0) && (h < 128) && (w >= 0) && (w < 128);
        if (ok) {
            xoff[k] = XQ_OFF + n * 4194304 + (h * 128 + w) * 32 + q * 16;
            xstr[k] = 524288;
        } else {
            xoff[k] = ZP_OFF + lane * 16;
            xstr[k] = 0;
        }
    }
    // ---- w staging: 3 gl_lds/wave (segs t = wv + 4k; t<9 real taps, t>=9 dummy)
    //   per-lane src: lane l -> (q = l>>5, o = o0 + (l&31)) of tap t, chunk cc.
    int woff[3];
    int wstr[3];
    #pragma unroll
    for (int k = 0; k < 3; ++k) {
        int t = wv + 4 * k;                  // 0..11
        if (t < 9) {
            woff[k] = WQB_OFF + ((t * 2 + q2) * 256 + o0 + m32) * 16;
            wstr[k] = 73728;
        } else {
            woff[k] = ZP_OFF + lane * 16;
            wstr[k] = 0;
        }
    }

    auto stage_x = [&](int tb) {
        #pragma unroll
        for (int k = 0; k < 5; ++k) {
            int s = wv + 4 * k;
            gl_lds16(wsb + xoff[k], (char*)&xs[tb][0] + s * 1024);
            xoff[k] += xstr[k];
        }
    };
    auto stage_w = [&](int tb) {
        #pragma unroll
        for (int k = 0; k < 3; ++k) {
            int t = wv + 4 * k;
            char* dst = (t < 9) ? ((char*)&wl[tb][0] + t * 1024) : (char*)&wdump[0];
            gl_lds16(wsb + woff[k], dst);
            woff[k] += wstr[k];
        }
    };

    // ---- scale/bias to LDS (visible by first barrier; read only in epilogue)
    if (tid < 32) {
        float fwv = wsf[64 + o0 + tid];
        sc[tid] = 1.0f / (fx * fwv);
        bz[tid] = bias[o0 + tid];
    }

    floatx16 acc[4];
    #pragma unroll
    for (int p = 0; p < 4; ++p)
        #pragma unroll
        for (int e = 0; e < 16; ++e) acc[p][e] = 0.f;

    // ---- prologue: w(0), x(0), x(1) in flight (issue order matters for vmcnt math)
    stage_w(0);
    stage_x(0);
    stage_x(1);

    // ---- conflict-free read column bases
    int xrd = q2 * 544 + m32 * 16;           // + srow*1088 + kw*16
    int wrd = q2 * 512 + m32 * 16;           // + tap*1024

    // ---- K loop, fully unrolled. Per iter cc:
    //   barrier A; stage_w(cc+1); stage_x(cc+2); vmcnt(N); barrier E; compute chunk cc.
    //   N = |{x(cc+1), w(cc+1), x(cc+2)}| = 13 (cc<6), 8 (cc=6), 0 (cc=7): in-order
    //   retirement => w(cc) retired => x(cc) retired => buffers cc valid after barrier E.
    #pragma unroll
    for (int cc = 0; cc < 8; ++cc) {
        __builtin_amdgcn_s_barrier();                       // recycled buffers free
        if (cc < 7) stage_w((cc + 1) & 1);
        if (cc < 6) stage_x((cc + 2) % 3);
        if (cc < 6)       asm volatile("s_waitcnt vmcnt(13)" ::: "memory");
        else if (cc == 6) asm volatile("s_waitcnt vmcnt(8)" ::: "memory");
        else              asm volatile("s_waitcnt vmcnt(0)" ::: "memory");
        __builtin_amdgcn_s_barrier();                       // chunk cc buffers valid
        __builtin_amdgcn_sched_barrier(0);                  // no ds_read hoist above

        const char* xb = (const char*)&xs[cc % 3][0] + wv * (4 * 1088) + xrd;
        const char* wb = (const char*)&wl[cc & 1][0] + wrd;
        #pragma unroll
        for (int kw = 0; kw < 3; ++kw) {
            half8 xf[6];
            #pragma unroll
            for (int srow = 0; srow < 6; ++srow)
                xf[srow] = *(const half8*)(xb + srow * 1088 + kw * 16);
            half8 wf[3];
            #pragma unroll
            for (int kh = 0; kh < 3; ++kh)
                wf[kh] = *(const half8*)(wb + (kh * 3 + kw) * 1024);
            __builtin_amdgcn_s_setprio(1);
            #pragma unroll
            for (int kh = 0; kh < 3; ++kh) {
                #pragma unroll
                for (int p = 0; p < 4; ++p)
                    acc[p] = __builtin_amdgcn_mfma_f32_32x32x16_f16(wf[kh], xf[p + kh], acc[p], 0, 0, 0);
            }
            __builtin_amdgcn_s_setprio(0);
        }
    }

    // ---- epilogue: D row = o (reg), col = pixel (lane) -> coalesced stores
    #pragma unroll
    for (int e = 0; e < 16; ++e) {
        int o_loc = (e & 3) + 8 * (e >> 2) + 4 * q2;
        float scale = sc[o_loc];
        float bv = bz[o_loc];
        #pragma unroll
        for (int p = 0; p < 4; ++p) {
            int h = h0 + wv * 4 + p;
            float v = fmaxf(fmaf(acc[p][e], scale, bv), 0.f);
            out[(((size_t)(n * 256 + o0 + o_loc)) * 128 + h) * 128 + w0 + m32] = v;
        }
    }
}

// ---------------- fallback (R2 kernel, used if ws too small) ----------------
__global__ __launch_bounds__(256, 2) void conv_fallback(const float* __restrict__ x,
                                                        const float* __restrict__ bias,
                                                        const float* __restrict__ wsf,
                                                        float* __restrict__ out) {
    __shared__ __align__(16) _Float16 xs[6 * JW * CKP];
    __shared__ __align__(16) _Float16 wlds[9 * 64 * CKP];

    const unsigned int* wsu = (const unsigned int*)wsf;
    float xmax = __uint_as_float(wsu[0]);
    float fx = xmax > 0.f ? FX_NUM / xmax : 1.0f;

    int bx = blockIdx.x;
    int n  = bx >> 5;
    int h0 = (bx & 31) << 2;
    int o0 = blockIdx.y << 6;

    int tid  = threadIdx.x;
    int lane = tid & 63;
    int wave = tid >> 6;
    int m32  = lane & 31;
    int q2   = lane >> 5;

    const _Float16* wq16 = (const _Float16*)((const char*)wsf + WQA_OFF);
    const float* xn = x + (size_t)n * (128 * 128 * 128);

    floatx16 acc[4][2];
    #pragma unroll
    for (int mt = 0; mt < 4; mt++)
        #pragma unroll
        for (int nt = 0; nt < 2; nt++)
            #pragma unroll
            for (int e = 0; e < 16; e++) acc[mt][nt][e] = 0.f;

    if (tid < 192) {
        int r = tid >> 5;
        int s = tid & 31;
        int c = s & 15;
        int j = (s >> 4) ? (JW - 1) : 0;
        xs[(r * JW + j) * CKP + c] = (_Float16)0.f;
    }

    for (int c0 = 0; c0 < 128; c0 += CK) {
        __syncthreads();
        #pragma unroll
        for (int it = 0; it < 12; ++it) {
            int idx = tid + it * 256;
            int j  = (idx & 127) + 1;
            int c4 = (idx >> 7) & 3;
            int r  = idx >> 9;
            int h  = h0 + r - 1;
            float v0 = 0.f, v1 = 0.f, v2 = 0.f, v3 = 0.f;
            if (h >= 0 && h < 128) {
                const float* xp = xn + (size_t)(c0 + c4 * 4) * 16384 + h * 128 + (j - 1);
                v0 = xp[0]; v1 = xp[16384]; v2 = xp[32768]; v3 = xp[49152];
            }
            half4 hv;
            hv[0] = (_Float16)rintf(fx * v0);
            hv[1] = (_Float16)rintf(fx * v1);
            hv[2] = (_Float16)rintf(fx * v2);
            hv[3] = (_Float16)rintf(fx * v3);
            *(half4*)&xs[(r * JW + j) * CKP + c4 * 4] = hv;
        }
        #pragma unroll
        for (int it = 0; it < 5; ++it) {
            int idx = tid + it * 256;
            if (idx < 1152) {
                int o   = idx / 18;
                int rem = idx - o * 18;
                int tap = rem >> 1;
                int g   = rem & 1;
                half8 v = *(const half8*)(wq16 + ((size_t)(o0 + o) * 9 + tap) * 128 + c0 + g * 8);
                *(half8*)&wlds[(tap * 64 + o) * CKP + g * 8] = v;
            }
        }
        __syncthreads();

        const _Float16* xbase = &xs[(wave * JW + m32) * CKP + q2 * 8];
        const _Float16* wbase = &wlds[m32 * CKP + q2 * 8];
        #pragma unroll
        for (int kh = 0; kh < 3; ++kh) {
            #pragma unroll
            for (int kw = 0; kw < 3; ++kw) {
                int tap = kh * 3 + kw;
                half8 b0 = *(const half8*)(wbase + (tap * 64 +  0) * CKP);
                half8 b1 = *(const half8*)(wbase + (tap * 64 + 32) * CKP);
                #pragma unroll
                for (int mt = 0; mt < 4; ++mt) {
                    half8 a = *(const half8*)(xbase + (kh * JW + kw + mt * 32) * CKP);
                    acc[mt][0] = __builtin_amdgcn_mfma_f32_32x32x16_f16(a, b0, acc[mt][0], 0, 0, 0);
                    acc[mt][1] = __builtin_amdgcn_mfma_f32_32x32x16_f16(a, b1, acc[mt][1], 0, 0, 0);
                }
            }
        }
    }

    int h = h0 + wave;
    #pragma unroll
    for (int nt = 0; nt < 2; ++nt) {
        int o = o0 + nt * 32 + m32;
        float fwv = wsf[64 + o];
        float scale = 1.0f / (fx * fwv);
        float bv = bias[o];
        float* op = out + (((size_t)n * 256 + o) * 128 + h) * 128;
        #pragma unroll
        for (int mt = 0; mt < 4; ++mt) {
            #pragma unroll
            for (int g = 0; g < 4; ++g) {
                int w = mt * 32 + 8 * g + 4 * q2;
                float4 r;
                r.x = fmaxf(fmaf(acc[mt][nt][4 * g + 0], scale, bv), 0.f);
                r.y = fmaxf(fmaf(acc[mt][nt][4 * g + 1], scale, bv), 0.f);
                r.z = fmaxf(fmaf(acc[mt][nt][4 * g + 2], scale, bv), 0.f);
                r.w = fmaxf(fmaf(acc[mt][nt][4 * g + 3], scale, bv), 0.f);
                *(float4*)(op + w) = r;
            }
        }
    }
}

extern "C" void kernel_launch(void* const* d_in, const int* in_sizes, int n_in,
                              void* d_out, int out_size, void* d_ws, size_t ws_size,
                              hipStream_t stream) {
    const float* x = (const float*)d_in[0];   // [16,128,128,128]
    const float* W = (const float*)d_in[1];   // [256,128,3,3]
    const float* b = (const float*)d_in[2];   // [256]
    float* out = (float*)d_out;
    float* wsf = (float*)d_ws;

    int big = (ws_size >= (size_t)XQ_OFF + XQ_BYTES) ? 1 : 0;

    hipMemsetAsync(d_ws, 0, 256, stream);     // xmax slot (ws poisoned 0xAA)
    if (big)
        hipMemsetAsync((char*)d_ws + ZP_OFF, 0, 2048, stream);   // zero page for OOB staging

    xmax_kernel<<<1024, 256, 0, stream>>>(x, (unsigned int*)d_ws, (16 * 128 * 128 * 128) / 4);
    wq_kernel<<<256, 128, 0, stream>>>(W, wsf, big);

    if (big) {
        _Float16* xq = (_Float16*)((char*)d_ws + XQ_OFF);
        quantx_kernel<<<16 * 8 * 128, 128, 0, stream>>>(x, wsf, xq);
        conv_main<<<4096, 256, 0, stream>>>(xq, b, wsf, out);
    } else {
        dim3 grid(512, 4);
        conv_fallback<<<grid, 4 * 64, 0, stream>>>(x, b, wsf, out);
    }
}